// Round 12
// baseline (275.261 us; speedup 1.0000x reference)
//
#include <hip/hip_runtime.h>

#define NB 8192
#define NT 365
#define NF 5
#define NH 10
#define NG 40   // 4*NH
#define GPW 6   // 10-lane groups per wave (lanes 60..63 dead)

// One lane owns ONE hidden unit u: its 4 gate columns (f,i,o,g order, i.e.
// w[:, u], w[:,10+u], w[:,20+u], w[:,30+u]), its c[u], h[u], and the stores
// h_n[b,t,u], c_n[b,t,u]  (contiguous across the 10-lane group -> coalesced).
// Activation + cell update are fully lane-local (no DPP, no replication).
// The only cross-lane op: broadcast the 10 fresh h values within the group
// via 10 ds_bpermute. g-gate weights/bias pre-scaled x2 (tanh(x)=2sig(2x)-1).
// x-projection for step t+1 is computed at the end of step t (fills stalls).
__global__ __launch_bounds__(256, 1)
void lstm_unit(const float* __restrict__ x,
               const float* __restrict__ w_ih,
               const float* __restrict__ w_hh,
               const float* __restrict__ bias,
               const float* __restrict__ fc_w,
               const float* __restrict__ fc_b,
               float* __restrict__ out)
{
    const int lane = threadIdx.x & 63;
    const int wid  = (blockIdx.x * 256 + threadIdx.x) >> 6;  // global wave id
    const int g    = lane / NH;          // group in wave (0..5; 6 => dead lane)
    const int u    = lane % NH;          // owned hidden unit
    const long b0  = (long)wid * GPW + g;
    const bool alive = (g < GPW) && (b0 < NB);
    const long b   = alive ? b0 : 0;     // clamped for safe addressing

    float* h_out = out + NB;
    float* c_out = h_out + (size_t)NB * NT * NH;

    // ---- per-lane weights: 4 columns x (5 ih + 10 hh) + 4 bias ----
    float wih[NF][4], whh[NH][4], bq[4];
    #pragma unroll
    for (int q = 0; q < 4; ++q) {
        const float gs = (q == 3) ? 2.0f : 1.0f;
        const int col = q * NH + u;
        #pragma unroll
        for (int f = 0; f < NF; ++f) wih[f][q] = w_ih[f * NG + col] * gs;
        #pragma unroll
        for (int j = 0; j < NH; ++j) whh[j][q] = w_hh[j * NG + col] * gs;
        bq[q] = bias[col] * gs;
    }

    // bpermute byte-addresses of the 10 group members (set up once)
    int aj[NH];
    #pragma unroll
    for (int j = 0; j < NH; ++j) aj[j] = (g * NH + j) * 4;

    float hAll[NH];
    #pragma unroll
    for (int j = 0; j < NH; ++j) hAll[j] = 0.f;
    float c = 0.f;

    const float* xp = x + (size_t)b * NT * NF;
    float* hp = h_out + (size_t)b * NT * NH + u;
    float* cp = c_out + (size_t)b * NT * NH + u;

    // xa[q] = bias + x_t . wih  (one step ahead)
    float xa[4];
    {
        float x0[NF];
        #pragma unroll
        for (int f = 0; f < NF; ++f) x0[f] = xp[f];
        #pragma unroll
        for (int q = 0; q < 4; ++q) {
            float a = bq[q];
            #pragma unroll
            for (int f = 0; f < NF; ++f) a = fmaf(x0[f], wih[f][q], a);
            xa[q] = a;
        }
    }

    for (int t = 0; t < NT; ++t) {
        // next-step x loads issued early
        float xn[NF];
        const float* xnp = xp + (size_t)((t + 1 < NT) ? (t + 1) : t) * NF;
        #pragma unroll
        for (int f = 0; f < NF; ++f) xn[f] = xnp[f];

        // ---- 4 gate pre-activations for hidden unit u ----
        float r[4];
        #pragma unroll
        for (int q = 0; q < 4; ++q) {
            float a = xa[q];
            #pragma unroll
            for (int j = 0; j < NH; ++j) a = fmaf(hAll[j], whh[j][q], a);
            r[q] = a;
        }
        // ---- activations (g pre-scaled: tanh(x)=2*sigmoid(2x)-1) ----
        float sf = __builtin_amdgcn_rcpf(1.0f + __expf(-r[0]));
        float si = __builtin_amdgcn_rcpf(1.0f + __expf(-r[1]));
        float so = __builtin_amdgcn_rcpf(1.0f + __expf(-r[2]));
        float tg = fmaf(2.0f, __builtin_amdgcn_rcpf(1.0f + __expf(-r[3])), -1.0f);

        // ---- cell update (lane-local) ----
        c = fmaf(sf, c, si * tg);
        float th = fmaf(2.0f, __builtin_amdgcn_rcpf(1.0f + __expf(-2.0f * c)), -1.0f);
        float h = so * th;

        // ---- broadcast the group's 10 h values ----
        #pragma unroll
        for (int j = 0; j < NH; ++j)
            hAll[j] = __int_as_float(
                __builtin_amdgcn_ds_bpermute(aj[j], __float_as_int(h)));

        // ---- stores (coalesced within group; dead lanes masked) ----
        if (alive) {
            hp[(size_t)t * NH] = h;
            cp[(size_t)t * NH] = c;
        }

        // ---- next step's x-projection (independent, fills stall slots) ----
        #pragma unroll
        for (int q = 0; q < 4; ++q) {
            float a = bq[q];
            #pragma unroll
            for (int f = 0; f < NF; ++f) a = fmaf(xn[f], wih[f][q], a);
            xa[q] = a;
        }
    }

    // ---- fc head: lane u==0 of each live group has hAll = h_{T-1} ----
    if (alive && u == 0) {
        float acc = fc_b[0];
        #pragma unroll
        for (int j = 0; j < NH; ++j) acc = fmaf(hAll[j], fc_w[j], acc);
        out[b] = acc;
    }
}

extern "C" void kernel_launch(void* const* d_in, const int* in_sizes, int n_in,
                              void* d_out, int out_size, void* d_ws, size_t ws_size,
                              hipStream_t stream) {
    const float* x    = (const float*)d_in[0];
    const float* wih  = (const float*)d_in[1];
    const float* whh  = (const float*)d_in[2];
    const float* bias = (const float*)d_in[3];
    const float* fcw  = (const float*)d_in[4];
    const float* fcb  = (const float*)d_in[5];
    float* out = (float*)d_out;

    const int nwave  = (NB + GPW - 1) / GPW;          // 1366 waves of work
    const int blocks = (nwave * 64 + 255) / 256;      // 342 blocks (tail dead)
    lstm_unit<<<blocks, 256, 0, stream>>>(x, wih, whh, bias, fcw, fcb, out);
}

// Round 13
// 175.525 us; speedup vs baseline: 1.5682x; 1.5682x over previous
//
#include <hip/hip_runtime.h>

#define NB 8192
#define NT 365
#define NF 5
#define NH 10
#define NG 40   // 4*NH
#define GPW 6   // 10-lane groups per wave (lanes 60..63 dead)

// One lane owns ONE hidden unit u (its 4 gate columns f,i,o,g; c[u]; h[u]).
// Cross-lane traffic: 10 ds_bpermute per step to broadcast the group's h.
// g-gate weights/bias pre-scaled x2 (tanh(x) = 2*sigmoid(2x)-1).
//
// NEW vs r12: x is prefetched in 8-step chunks of 10 aligned float4 into a
// register double-buffer (A/B). Loads for chunk c+1 are issued BEFORE the 8
// steps of chunk c run, giving ~2400 cycles of latency cover (vs 1 step =
// ~300 cycles before). Steady-state step has no global loads at all.
__global__ __launch_bounds__(256, 1)
void lstm_unit_px(const float* __restrict__ x,
                  const float* __restrict__ w_ih,
                  const float* __restrict__ w_hh,
                  const float* __restrict__ bias,
                  const float* __restrict__ fc_w,
                  const float* __restrict__ fc_b,
                  float* __restrict__ out)
{
    const int lane = threadIdx.x & 63;
    const int wid  = (blockIdx.x * 256 + threadIdx.x) >> 6;  // global wave id
    const int g    = lane / NH;          // group in wave (0..5; 6 => dead)
    const int u    = lane % NH;          // owned hidden unit
    const long b0  = (long)wid * GPW + g;
    const bool alive = (g < GPW) && (b0 < NB);
    const long b   = alive ? b0 : 0;     // clamped for safe addressing

    float* h_out = out + NB;
    float* c_out = h_out + (size_t)NB * NT * NH;

    // ---- per-lane weights: 4 columns x (5 ih + 10 hh) + 4 bias ----
    float wih[NF][4], whh[NH][4], bq[4];
    #pragma unroll
    for (int q = 0; q < 4; ++q) {
        const float gs = (q == 3) ? 2.0f : 1.0f;
        const int col = q * NH + u;
        #pragma unroll
        for (int f = 0; f < NF; ++f) wih[f][q] = w_ih[f * NG + col] * gs;
        #pragma unroll
        for (int j = 0; j < NH; ++j) whh[j][q] = w_hh[j * NG + col] * gs;
        bq[q] = bias[col] * gs;
    }

    // bpermute byte-addresses of the 10 group members
    int aj[NH];
    #pragma unroll
    for (int j = 0; j < NH; ++j) aj[j] = (g * NH + j) * 4;

    float hAll[NH];
    #pragma unroll
    for (int j = 0; j < NH; ++j) hAll[j] = 0.f;
    float c = 0.f;

    const float* xp = x + (size_t)b * NT * NF;           // 16B-aligned: b*29200
    float* hcp = h_out + (size_t)b * NT * NH + u;
    float* ccp = c_out + (size_t)b * NT * NH + u;

    float A[40], B[40];   // x double-buffer: 8 steps x 5 features each

// load one 8-step chunk (40 contiguous floats, 10 aligned float4)
#define LD8(dst, t0) { \
    const float4* p4 = reinterpret_cast<const float4*>(xp + (size_t)(t0) * NF); \
    _Pragma("unroll") \
    for (int i = 0; i < 10; ++i) { \
        float4 v = p4[i]; \
        dst[i*4+0] = v.x; dst[i*4+1] = v.y; dst[i*4+2] = v.z; dst[i*4+3] = v.w; } }

// tail: 5 steps = 25 floats (6 float4 + 1 dword), exactly to end of row
#define LDT(dst) { \
    const float4* p4 = reinterpret_cast<const float4*>(xp + (size_t)360 * NF); \
    _Pragma("unroll") \
    for (int i = 0; i < 6; ++i) { \
        float4 v = p4[i]; \
        dst[i*4+0] = v.x; dst[i*4+1] = v.y; dst[i*4+2] = v.z; dst[i*4+3] = v.w; } \
    dst[24] = xp[360 * NF + 24]; }

// one LSTM step; s is a literal -> all buf indices compile-time constants
#define STEP(buf, s) { \
    float r0 = bq[0], r1 = bq[1], r2 = bq[2], r3 = bq[3]; \
    _Pragma("unroll") \
    for (int f = 0; f < NF; ++f) { \
        const float xv = buf[(s) * NF + f]; \
        r0 = fmaf(xv, wih[f][0], r0); r1 = fmaf(xv, wih[f][1], r1); \
        r2 = fmaf(xv, wih[f][2], r2); r3 = fmaf(xv, wih[f][3], r3); } \
    _Pragma("unroll") \
    for (int j = 0; j < NH; ++j) { \
        const float hv = hAll[j]; \
        r0 = fmaf(hv, whh[j][0], r0); r1 = fmaf(hv, whh[j][1], r1); \
        r2 = fmaf(hv, whh[j][2], r2); r3 = fmaf(hv, whh[j][3], r3); } \
    const float sf = __builtin_amdgcn_rcpf(1.0f + __expf(-r0)); \
    const float si = __builtin_amdgcn_rcpf(1.0f + __expf(-r1)); \
    const float so = __builtin_amdgcn_rcpf(1.0f + __expf(-r2)); \
    const float tg = fmaf(2.0f, __builtin_amdgcn_rcpf(1.0f + __expf(-r3)), -1.0f); \
    c = fmaf(sf, c, si * tg); \
    const float th = fmaf(2.0f, __builtin_amdgcn_rcpf(1.0f + __expf(-2.0f * c)), -1.0f); \
    const float h = so * th; \
    _Pragma("unroll") \
    for (int j = 0; j < NH; ++j) \
        hAll[j] = __int_as_float(__builtin_amdgcn_ds_bpermute(aj[j], __float_as_int(h))); \
    if (alive) { hcp[(s) * NH] = h; ccp[(s) * NH] = c; } }

#define RUN8(buf) { STEP(buf,0) STEP(buf,1) STEP(buf,2) STEP(buf,3) \
                    STEP(buf,4) STEP(buf,5) STEP(buf,6) STEP(buf,7) \
                    hcp += 8 * NH; ccp += 8 * NH; }

    LD8(A, 0)
    // 44 full chunks in 22 statically ping-ponged pairs: t = 0..351
    for (int cc = 0; cc < 22; ++cc) {
        const int t0 = cc * 16;
        LD8(B, t0 + 8)      // prefetch next chunk, then run current
        RUN8(A)
        LD8(A, t0 + 16)     // cc=21 -> t=352 (floats [1760,1800) < 1825: in-bounds)
        RUN8(B)
    }
    // A holds chunk t=352..359; prefetch tail, run, then 5 tail steps
    LDT(B)
    RUN8(A)
    { STEP(B,0) STEP(B,1) STEP(B,2) STEP(B,3) STEP(B,4) }   // t=360..364

    // ---- fc head: lane u==0 of each live group has hAll = h_{T-1} ----
    if (alive && u == 0) {
        float acc = fc_b[0];
        #pragma unroll
        for (int j = 0; j < NH; ++j) acc = fmaf(hAll[j], fc_w[j], acc);
        out[b] = acc;
    }
}

extern "C" void kernel_launch(void* const* d_in, const int* in_sizes, int n_in,
                              void* d_out, int out_size, void* d_ws, size_t ws_size,
                              hipStream_t stream) {
    const float* x    = (const float*)d_in[0];
    const float* wih  = (const float*)d_in[1];
    const float* whh  = (const float*)d_in[2];
    const float* bias = (const float*)d_in[3];
    const float* fcw  = (const float*)d_in[4];
    const float* fcb  = (const float*)d_in[5];
    float* out = (float*)d_out;

    const int nwave  = (NB + GPW - 1) / GPW;          // 1366 waves of work
    const int blocks = (nwave * 64 + 255) / 256;      // 342 blocks
    lstm_unit_px<<<blocks, 256, 0, stream>>>(x, wih, whh, bias, fcw, fcb, out);
}